// Round 16
// baseline (390.563 us; speedup 1.0000x reference)
//
#include <hip/hip_runtime.h>
#include <stdint.h>

#define LSEQ 1024
#define EDIM 32
#define NDIM 64

typedef __attribute__((ext_vector_type(8))) short short8;
typedef __attribute__((ext_vector_type(4))) float f32x4;

static __device__ __forceinline__ unsigned short f2bf(float f) {
    unsigned int u = __float_as_uint(f);
    u += 0x7FFFu + ((u >> 16) & 1u);
    return (unsigned short)(u >> 16);
}

// Kernel A: niB = node@Wi + b_pair, njB = node@Wj (f32); wpT = (Wp + I)^T bf16;
// also zeroes the per-row completion counters for kernel B's fused finish.
__global__ __launch_bounds__(256) void evo_pre(
    const float* __restrict__ node,   // [1024][64]
    const float* __restrict__ Wpair,  // [160][32]
    const float* __restrict__ bpair,  // [32]
    float* __restrict__ niB,          // [1024][32]
    float* __restrict__ njB,          // [1024][32]
    unsigned short* __restrict__ wpT, // [32][32] bf16, row f, col e
    int* __restrict__ rowcnt)         // [1024]
{
    int g = blockIdx.x * 256 + threadIdx.x;
    if (g < LSEQ * EDIM) {
        int i = g >> 5, f = g & 31;
        float acci = bpair[f];
        float accj = 0.0f;
        const float* nrow = node + i * NDIM;
        #pragma unroll
        for (int k = 0; k < NDIM; ++k) {
            float nv = nrow[k];
            acci += nv * Wpair[k * 32 + f];
            accj += nv * Wpair[(64 + k) * 32 + f];
        }
        niB[g] = acci;
        njB[g] = accj;
    } else if (g < LSEQ * EDIM + EDIM * EDIM) {
        int idx = g - LSEQ * EDIM;
        int f = idx >> 5, e = idx & 31;
        float v = Wpair[(128 + e) * 32 + f];
        if (e == f) v += 1.0f;  // fold the +pair residual into the matmul
        wpT[f * 32 + e] = f2bf(v);
    } else {
        int idx = g - LSEQ * EDIM - EDIM * EDIM;
        if (idx < LSEQ) rowcnt[idx] = 0;
    }
}

// Kernel B: 2048 blocks = 2 per row i; block (4 waves) owns 512 j's, wave 128.
// Dense global streams; XOR-swizzled LDS in-tile and out-stage; NT full-line
// stores. FUSED FINISH: the second block of each row to complete (device-scope
// atomicAdd) computes the node update + LayerNorm for that row in-block.
__global__ __launch_bounds__(256, 4) void evo_main(
    const float* __restrict__ pair,   // [1024][1024][32]
    const float* __restrict__ node,   // [1024][64]
    const float* __restrict__ niB,    // [1024][32]
    const float* __restrict__ njB,    // [1024][32]
    const unsigned short* __restrict__ wpT,  // [32][32] bf16
    const float* __restrict__ Wnode,  // [96][64]
    const float* __restrict__ bnode,  // [64]
    const float* __restrict__ lnsc,   // [64]
    const float* __restrict__ lnof,   // [64]
    float* __restrict__ partial,      // [2048][32]
    int* __restrict__ rowcnt,         // [1024]
    float* __restrict__ out_node,     // [1024][64]
    float* __restrict__ out_pair)     // [1024][1024][32]
{
    __shared__ float tin[4][512];     // per-wave 2-KB input tile (chunk-XOR)
    __shared__ float stage[4][512];   // per-wave 2-KB output stage (R9 layout)
    __shared__ float red[4][32];
    __shared__ float node_f[64];
    __shared__ float p2n[32];
    __shared__ int   winflag;

    const int blk  = blockIdx.x;
    const int i    = blk >> 1;
    const int h    = blk & 1;
    const int tid  = threadIdx.x;
    const int wave = tid >> 6;
    const int lane = tid & 63;
    const int c    = lane & 15;   // frag: j-col select
    const int a    = lane >> 4;   // frag: k-chunk select
    const int q    = lane & 7;    // dense: 16-B chunk within row
    const int r0   = lane >> 3;   // dense: row within half-tile

    const short8 af0 = *(const short8*)(wpT + c * 32 + a * 8);
    const short8 af1 = *(const short8*)(wpT + (c + 16) * 32 + a * 8);
    const f32x4 ni_d = *(const f32x4*)(niB + i * 32 + q * 4);

    const int jw = (h << 9) + (wave << 7);
    const size_t tb = ((size_t)i * 1024 + (size_t)jw) * 32;
    const float* pinD = pair + tb + lane * 4;                   // dense in
    const float* njD  = njB + (size_t)(jw + r0) * 32 + q * 4;   // dense nj
    float*       preg = out_pair + tb + lane * 4;               // dense out

    const int xin = (q ^ (r0 & 7)) * 4;
    float* inW0 = &tin[wave][r0 * 32 + xin];
    float* inW1 = inW0 + 256;
    const float* bf0p = &tin[wave][c * 32 + (((2 * a)     ^ (c & 7)) * 4)];
    const float* bf1p = &tin[wave][c * 32 + (((2 * a + 1) ^ (c & 7)) * 4)];

    const int key = (c & 7) << 2;
    float* wr0 = &stage[wave][c * 32 + ((4 * a) ^ key)];
    float* wr1 = &stage[wave][c * 32 + ((16 + 4 * a) ^ key)];
    const float* rd0 = &stage[wave][r0 * 32 + ((q * 4) ^ ((r0 & 7) << 2))];
    const float* rd1 = rd0 + 256;

    f32x4 P0[2], P1[2], J0[2], J1[2];
    P0[0] = *(const f32x4*)(pinD);
    P1[0] = *(const f32x4*)(pinD + 256);
    J0[0] = *(const f32x4*)(njD);
    J1[0] = *(const f32x4*)(njD + 256);

    f32x4 sumd = {0.f, 0.f, 0.f, 0.f};

    #pragma unroll
    for (int t = 0; t < 8; ++t) {
        const int cur = t & 1, nxt = cur ^ 1;
        if (t < 7) {
            P0[nxt] = *(const f32x4*)(pinD + (t + 1) * 512);
            P1[nxt] = *(const f32x4*)(pinD + (t + 1) * 512 + 256);
            J0[nxt] = *(const f32x4*)(njD + (t + 1) * 512);
            J1[nxt] = *(const f32x4*)(njD + (t + 1) * 512 + 256);
        }

        *(f32x4*)inW0 = P0[cur];
        *(f32x4*)inW1 = P1[cur];

        const f32x4 b0 = *(const f32x4*)bf0p;
        const f32x4 b1 = *(const f32x4*)bf1p;
        short8 bfrag;
        bfrag[0] = (short)f2bf(b0.x); bfrag[1] = (short)f2bf(b0.y);
        bfrag[2] = (short)f2bf(b0.z); bfrag[3] = (short)f2bf(b0.w);
        bfrag[4] = (short)f2bf(b1.x); bfrag[5] = (short)f2bf(b1.y);
        bfrag[6] = (short)f2bf(b1.z); bfrag[7] = (short)f2bf(b1.w);
        const f32x4 z = {0.f, 0.f, 0.f, 0.f};
        const f32x4 acc0 = __builtin_amdgcn_mfma_f32_16x16x32_bf16(af0, bfrag, z, 0, 0, 0);
        const f32x4 acc1 = __builtin_amdgcn_mfma_f32_16x16x32_bf16(af1, bfrag, z, 0, 0, 0);

        *(f32x4*)wr0 = acc0;
        *(f32x4*)wr1 = acc1;
        const f32x4 d0 = *(const f32x4*)rd0 + ni_d + J0[cur];
        const f32x4 d1 = *(const f32x4*)rd1 + ni_d + J1[cur];
        sumd += d0 + d1;
        __builtin_nontemporal_store(d0, (f32x4*)(preg + t * 512));
        __builtin_nontemporal_store(d1, (f32x4*)(preg + t * 512 + 256));
    }

    // reduce j-sums over rows (lanes sharing q hold disjoint rows)
    for (int m = 8; m < 64; m <<= 1) {
        sumd.x += __shfl_xor(sumd.x, m);
        sumd.y += __shfl_xor(sumd.y, m);
        sumd.z += __shfl_xor(sumd.z, m);
        sumd.w += __shfl_xor(sumd.w, m);
    }
    if (lane < 8) *(f32x4*)&red[wave][q * 4] = sumd;
    __syncthreads();

    float myp = 0.0f;
    if (tid < 32) {
        myp = red[0][tid] + red[1][tid] + red[2][tid] + red[3][tid];
        partial[blk * 32 + tid] = myp;
    }
    __threadfence();   // release the partial store device-wide
    __syncthreads();
    if (tid == 0) {
        int prev = __hip_atomic_fetch_add(rowcnt + i, 1, __ATOMIC_ACQ_REL,
                                          __HIP_MEMORY_SCOPE_AGENT);
        winflag = (prev == 1);
    }
    __syncthreads();

    if (winflag) {  // block-uniform: fused node update + LayerNorm for row i
        if (tid < 64) node_f[tid] = node[i * 64 + tid];
        if (tid < 32) {
            float o = __hip_atomic_load(partial + ((blk ^ 1) * 32 + tid),
                                        __ATOMIC_ACQUIRE, __HIP_MEMORY_SCOPE_AGENT);
            p2n[tid] = (myp + o) * (1.0f / 1024.0f);
        }
        __syncthreads();
        if (tid < 64) {
            float acc = node_f[tid] + bnode[tid];
            #pragma unroll 8
            for (int k = 0; k < 64; ++k)
                acc += node_f[k] * Wnode[k * 64 + tid];
            #pragma unroll 8
            for (int k = 0; k < 32; ++k)
                acc += p2n[k] * Wnode[(64 + k) * 64 + tid];
            float s = acc, s2 = acc * acc;
            for (int m = 1; m < 64; m <<= 1) {
                s  += __shfl_xor(s, m);
                s2 += __shfl_xor(s2, m);
            }
            const float mean = s * (1.0f / 64.0f);
            const float var  = s2 * (1.0f / 64.0f) - mean * mean;
            const float y = (acc - mean) * rsqrtf(var + 1e-5f) * lnsc[tid] + lnof[tid];
            out_node[i * 64 + tid] = y;
        }
    }
}

extern "C" void kernel_launch(void* const* d_in, const int* in_sizes, int n_in,
                              void* d_out, int out_size, void* d_ws, size_t ws_size,
                              hipStream_t stream) {
    const float* node  = (const float*)d_in[0];
    const float* pair  = (const float*)d_in[1];
    const float* Wpair = (const float*)d_in[2];
    const float* bpair = (const float*)d_in[3];
    const float* Wnode = (const float*)d_in[4];
    const float* bnode = (const float*)d_in[5];
    const float* lnsc  = (const float*)d_in[6];
    const float* lnof  = (const float*)d_in[7];

    float* niB = (float*)d_ws;                        // [1024][32] f32
    float* njB = niB + LSEQ * EDIM;                   // [1024][32] f32
    unsigned short* wpT = (unsigned short*)(njB + LSEQ * EDIM);  // [32][32] bf16 (2 KB)
    float* partial = (float*)(wpT + EDIM * EDIM);     // [2048][32] f32 (256 KB)
    int* rowcnt = (int*)(partial + 2 * LSEQ * EDIM);  // [1024] int

    float* out_node = (float*)d_out;
    float* out_pair = out_node + LSEQ * NDIM;

    evo_pre<<<136, 256, 0, stream>>>(node, Wpair, bpair, niB, njB, wpT, rowcnt);
    evo_main<<<2 * LSEQ, 256, 0, stream>>>(pair, node, niB, njB, wpT,
                                           Wnode, bnode, lnsc, lnof,
                                           partial, rowcnt, out_node, out_pair);
}

// Round 17
// 55.257 us; speedup vs baseline: 7.0681x; 7.0681x over previous
//
#include <hip/hip_runtime.h>
#include <stdint.h>

#define LSEQ 1024
#define EDIM 32
#define NDIM 64

typedef __attribute__((ext_vector_type(8))) short short8;
typedef __attribute__((ext_vector_type(4))) float f32x4;

static __device__ __forceinline__ unsigned short f2bf(float f) {
    unsigned int u = __float_as_uint(f);
    u += 0x7FFFu + ((u >> 16) & 1u);
    return (unsigned short)(u >> 16);
}

// Kernel A: niB = node@Wi + b_pair, njB = node@Wj (f32); wpT = (Wp + I)^T in bf16
__global__ __launch_bounds__(256) void evo_pre(
    const float* __restrict__ node,   // [1024][64]
    const float* __restrict__ Wpair,  // [160][32]
    const float* __restrict__ bpair,  // [32]
    float* __restrict__ niB,          // [1024][32]
    float* __restrict__ njB,          // [1024][32]
    unsigned short* __restrict__ wpT) // [32][32] bf16, row f, col e
{
    int g = blockIdx.x * 256 + threadIdx.x;
    if (g < LSEQ * EDIM) {
        int i = g >> 5, f = g & 31;
        float acci = bpair[f];
        float accj = 0.0f;
        const float* nrow = node + i * NDIM;
        #pragma unroll
        for (int k = 0; k < NDIM; ++k) {
            float nv = nrow[k];
            acci += nv * Wpair[k * 32 + f];
            accj += nv * Wpair[(64 + k) * 32 + f];
        }
        niB[g] = acci;
        njB[g] = accj;
    } else {
        int idx = g - LSEQ * EDIM;
        if (idx < EDIM * EDIM) {
            int f = idx >> 5, e = idx & 31;
            float v = Wpair[(128 + e) * 32 + f];
            if (e == f) v += 1.0f;  // fold the +pair residual into the matmul
            wpT[f * 32 + e] = f2bf(v);
        }
    }
}

// Kernel B: 2048 blocks = 2 per row i; block (4 waves) owns 512 j's, wave 128.
// All global streams lane-ordered dense (1 KB contiguous per instruction).
// pair in -> dense load -> XOR-swizzled LDS in-tile -> frag ds_read -> MFMA
// MFMA out -> XOR-swizzled LDS out-stage -> dense read (+ni+nj) -> NT store
// (nt is safe here: every store instruction covers 8 FULL 128-B lines; and
//  NO device-scope fences anywhere — R16 showed nt + threadfence = 7x stall.)
__global__ __launch_bounds__(256, 4) void evo_main(
    const float* __restrict__ pair,   // [1024][1024][32]
    const float* __restrict__ niB,    // [1024][32]
    const float* __restrict__ njB,    // [1024][32]
    const unsigned short* __restrict__ wpT,  // [32][32] bf16
    float* __restrict__ partial,      // [2048][32]
    float* __restrict__ out_pair)     // [1024][1024][32]
{
    __shared__ float tin[4][512];     // per-wave 2-KB input tile (chunk-XOR layout)
    __shared__ float stage[4][512];   // per-wave 2-KB output stage (R9 layout)
    __shared__ float red[4][32];

    const int blk  = blockIdx.x;
    const int i    = blk >> 1;
    const int h    = blk & 1;
    const int tid  = threadIdx.x;
    const int wave = tid >> 6;
    const int lane = tid & 63;
    const int c    = lane & 15;   // frag: j-col select
    const int a    = lane >> 4;   // frag: k-chunk select
    const int q    = lane & 7;    // dense: 16-B chunk within row
    const int r0   = lane >> 3;   // dense: row within half-tile

    // A fragments (loop-invariant)
    const short8 af0 = *(const short8*)(wpT + c * 32 + a * 8);
    const short8 af1 = *(const short8*)(wpT + (c + 16) * 32 + a * 8);
    // ni bias, dense side: depends only on f-chunk q (loop-invariant)
    const f32x4 ni_d = *(const f32x4*)(niB + i * 32 + q * 4);

    const int jw = (h << 9) + (wave << 7);
    const size_t tb = ((size_t)i * 1024 + (size_t)jw) * 32;
    const float* pinD = pair + tb + lane * 4;                   // dense in
    const float* njD  = njB + (size_t)(jw + r0) * 32 + q * 4;   // dense nj
    float*       preg = out_pair + tb + lane * 4;               // dense out

    // LDS in-tile: write dense rows with 16-B chunk XOR; read frag pattern
    const int xin = (q ^ (r0 & 7)) * 4;
    float* inW0 = &tin[wave][r0 * 32 + xin];          // rows 0-7
    float* inW1 = inW0 + 256;                         // rows 8-15 (same key)
    const float* bf0p = &tin[wave][c * 32 + (((2 * a)     ^ (c & 7)) * 4)];
    const float* bf1p = &tin[wave][c * 32 + (((2 * a + 1) ^ (c & 7)) * 4)];

    // LDS out-stage (identical to R9; 0 bank conflicts measured)
    const int key = (c & 7) << 2;
    float* wr0 = &stage[wave][c * 32 + ((4 * a) ^ key)];
    float* wr1 = &stage[wave][c * 32 + ((16 + 4 * a) ^ key)];
    const float* rd0 = &stage[wave][r0 * 32 + ((q * 4) ^ ((r0 & 7) << 2))];
    const float* rd1 = rd0 + 256;

    // 1-deep double-buffered prefetch (pair + nj), static indices under unroll
    f32x4 P0[2], P1[2], J0[2], J1[2];
    P0[0] = *(const f32x4*)(pinD);
    P1[0] = *(const f32x4*)(pinD + 256);
    J0[0] = *(const f32x4*)(njD);
    J1[0] = *(const f32x4*)(njD + 256);

    f32x4 sumd = {0.f, 0.f, 0.f, 0.f};

    #pragma unroll
    for (int t = 0; t < 8; ++t) {
        const int cur = t & 1, nxt = cur ^ 1;
        if (t < 7) {
            P0[nxt] = *(const f32x4*)(pinD + (t + 1) * 512);
            P1[nxt] = *(const f32x4*)(pinD + (t + 1) * 512 + 256);
            J0[nxt] = *(const f32x4*)(njD + (t + 1) * 512);
            J1[nxt] = *(const f32x4*)(njD + (t + 1) * 512 + 256);
        }

        // dense regs -> swizzled LDS in-tile
        *(f32x4*)inW0 = P0[cur];
        *(f32x4*)inW1 = P1[cur];

        // frag read (conflict-free via XOR) + bf16 pack + MFMA
        const f32x4 b0 = *(const f32x4*)bf0p;
        const f32x4 b1 = *(const f32x4*)bf1p;
        short8 bfrag;
        bfrag[0] = (short)f2bf(b0.x); bfrag[1] = (short)f2bf(b0.y);
        bfrag[2] = (short)f2bf(b0.z); bfrag[3] = (short)f2bf(b0.w);
        bfrag[4] = (short)f2bf(b1.x); bfrag[5] = (short)f2bf(b1.y);
        bfrag[6] = (short)f2bf(b1.z); bfrag[7] = (short)f2bf(b1.w);
        const f32x4 z = {0.f, 0.f, 0.f, 0.f};
        const f32x4 acc0 = __builtin_amdgcn_mfma_f32_16x16x32_bf16(af0, bfrag, z, 0, 0, 0);
        const f32x4 acc1 = __builtin_amdgcn_mfma_f32_16x16x32_bf16(af1, bfrag, z, 0, 0, 0);

        // frag -> out-stage -> dense; bias on dense side; NT dense store
        *(f32x4*)wr0 = acc0;
        *(f32x4*)wr1 = acc1;
        const f32x4 d0 = *(const f32x4*)rd0 + ni_d + J0[cur];
        const f32x4 d1 = *(const f32x4*)rd1 + ni_d + J1[cur];
        sumd += d0 + d1;
        __builtin_nontemporal_store(d0, (f32x4*)(preg + t * 512));
        __builtin_nontemporal_store(d1, (f32x4*)(preg + t * 512 + 256));
    }

    // reduce j-sums over rows: lanes differing in bits 3..5 share f-chunk q
    for (int m = 8; m < 64; m <<= 1) {
        sumd.x += __shfl_xor(sumd.x, m);
        sumd.y += __shfl_xor(sumd.y, m);
        sumd.z += __shfl_xor(sumd.z, m);
        sumd.w += __shfl_xor(sumd.w, m);
    }
    if (lane < 8) *(f32x4*)&red[wave][q * 4] = sumd;
    __syncthreads();
    if (tid < 32) {
        partial[blk * 32 + tid] = red[0][tid] + red[1][tid] + red[2][tid] + red[3][tid];
    }
}

// Kernel C: node update + LayerNorm. One block (1 wave) per row i.
__global__ __launch_bounds__(64) void evo_finish(
    const float* __restrict__ node,     // [1024][64]
    const float* __restrict__ partial,  // [2048][32]
    const float* __restrict__ Wnode,    // [96][64]
    const float* __restrict__ bnode,    // [64]
    const float* __restrict__ lnsc,     // [64]
    const float* __restrict__ lnof,     // [64]
    float* __restrict__ out_node)       // [1024][64]
{
    __shared__ float node_f[64];
    __shared__ float p2n[32];
    const int i   = blockIdx.x;
    const int tid = threadIdx.x;

    node_f[tid] = node[i * 64 + tid];
    if (tid < 32) {
        p2n[tid] = (partial[(2 * i) * 32 + tid] + partial[(2 * i + 1) * 32 + tid])
                   * (1.0f / 1024.0f);
    }
    __syncthreads();

    float acc = node_f[tid] + bnode[tid];
    #pragma unroll 8
    for (int k = 0; k < 64; ++k)
        acc += node_f[k] * Wnode[k * 64 + tid];
    #pragma unroll 8
    for (int k = 0; k < 32; ++k)
        acc += p2n[k] * Wnode[(64 + k) * 64 + tid];

    float s = acc, s2 = acc * acc;
    for (int m = 1; m < 64; m <<= 1) {
        s  += __shfl_xor(s, m);
        s2 += __shfl_xor(s2, m);
    }
    const float mean = s * (1.0f / 64.0f);
    const float var  = s2 * (1.0f / 64.0f) - mean * mean;
    const float y = (acc - mean) * rsqrtf(var + 1e-5f) * lnsc[tid] + lnof[tid];
    out_node[i * 64 + tid] = y;
}

extern "C" void kernel_launch(void* const* d_in, const int* in_sizes, int n_in,
                              void* d_out, int out_size, void* d_ws, size_t ws_size,
                              hipStream_t stream) {
    const float* node  = (const float*)d_in[0];
    const float* pair  = (const float*)d_in[1];
    const float* Wpair = (const float*)d_in[2];
    const float* bpair = (const float*)d_in[3];
    const float* Wnode = (const float*)d_in[4];
    const float* bnode = (const float*)d_in[5];
    const float* lnsc  = (const float*)d_in[6];
    const float* lnof  = (const float*)d_in[7];

    float* niB = (float*)d_ws;                        // [1024][32] f32
    float* njB = niB + LSEQ * EDIM;                   // [1024][32] f32
    unsigned short* wpT = (unsigned short*)(njB + LSEQ * EDIM);  // [32][32] bf16 (2 KB)
    float* partial = (float*)(wpT + EDIM * EDIM);     // [2048][32] f32 (256 KB)

    float* out_node = (float*)d_out;
    float* out_pair = out_node + LSEQ * NDIM;

    evo_pre<<<132, 256, 0, stream>>>(node, Wpair, bpair, niB, njB, wpT);
    evo_main<<<2 * LSEQ, 256, 0, stream>>>(pair, niB, njB, wpT, partial, out_pair);
    evo_finish<<<LSEQ, 64, 0, stream>>>(node, partial, Wnode, bnode, lnsc, lnof,
                                        out_node);
}